// Round 5
// baseline (383.530 us; speedup 1.0000x reference)
//
#include <hip/hip_runtime.h>

// Problem constants (B,C,H,W = 32,64,64,64; K=1024)
#define NPTS   131072
#define CDIM   64
#define KCODES 1024
#define HW     4096
#define CHW    (CDIM*HW)
#define NELEM  8388608

#define NGROUP  64              // 1024 codes / 16 per MFMA col-tile
#define GSTRIDE 2304            // bytes/group: 1024 (hi half0) + 1024 (hi half1) + 256 (norms*1024)
#define WS_BP   8               // float offset of Bpack in ws
#define WS_WL   (WS_BP + (NGROUP*GSTRIDE)/4)   // wl_cnt (int), wl after +16
#define WLCAP   16384
#define NFB_BLOCKS 512          // 2048 fallback waves
#define THR_KEY (256u << 10)    // 256 granules = 0.25 in true-distance units

typedef __attribute__((ext_vector_type(8))) _Float16 f16x8;
typedef __attribute__((ext_vector_type(4))) float    f32x4;

__device__ inline unsigned umin3(unsigned a, unsigned b, unsigned c) {
    unsigned d; asm("v_min3_u32 %0, %1, %2, %3" : "=v"(d) : "v"(a), "v"(b), "v"(c)); return d;
}
__device__ inline unsigned umed3(unsigned a, unsigned b, unsigned c) {
    unsigned d; asm("v_med3_u32 %0, %1, %2, %3" : "=v"(d) : "v"(a), "v"(b), "v"(c)); return d;
}

// Build the lane-order packed codebook: for group g, lane l needs code g*16+(l&15),
// channels (l>>4)*8.. and 32+(l>>4)*8.. — stored so wave loads are contiguous 1KB.
__global__ void vq_prep(const float* __restrict__ emb, float* __restrict__ ws) {
    int t = blockIdx.x * 256 + threadIdx.x;          // grid 16*256 = 4096 = 64 groups * 64 lanes
    if (t == 0) { ws[0] = 0.0f; ((int*)(ws + WS_WL))[0] = 0; }
    int g = t >> 6, l = t & 63;
    int code = g * 16 + (l & 15);
    int ch0  = (l >> 4) * 8;
    char* bp = (char*)(ws + WS_BP) + g * GSTRIDE;
    const float* row = emb + code * CDIM;
    double s = 0.0;
    for (int c = 0; c < CDIM; ++c) { double v = row[c]; s += v * v; }
    *(float*)(bp + 2048 + l * 4) = (float)(s * 1024.0);   // ||e||^2 * 1024
    f16x8 h0, h1;
    #pragma unroll
    for (int j = 0; j < 8; ++j) {
        h0[j] = (_Float16)row[ch0 + j];
        h1[j] = (_Float16)row[32 + ch0 + j];
    }
    *(f16x8*)(bp + l * 16)        = h0;
    *(f16x8*)(bp + 1024 + l * 16) = h1;
}

// 256 threads = 4 waves; each wave owns 64 consecutive points.
__global__ __launch_bounds__(256, 2) void vq_main(
    const float* __restrict__ x, const float* __restrict__ emb,
    float* __restrict__ ws, float* __restrict__ out)
{
    const char* bp = (const char*)(ws + WS_BP);
    int* wl_cnt = (int*)(ws + WS_WL);
    int* wl = wl_cnt + 16;

    const int lane = threadIdx.x & 63;
    const int widx = threadIdx.x >> 6;
    const int wb   = (blockIdx.x * 4 + widx) * 64;
    const int lrow = lane & 15;
    const int lk   = lane >> 4;

    __shared__ int      s_idx[4][64];
    __shared__ unsigned s_gap[4][64];

    // ---- A fragments: f16 hi/lo split of (-2048*x); znorm = 1024*||z||^2 ----
    f16x8 ah[4][2], al[4][2];
    float znorm[4];
    #pragma unroll
    for (int m = 0; m < 4; ++m) {
        int p = wb + m * 16 + lrow;
        const float* xb = x + (p >> 12) * CHW + (p & (HW - 1));
        float zsq = 0.f;
        #pragma unroll
        for (int h = 0; h < 2; ++h) {
            #pragma unroll
            for (int j = 0; j < 8; ++j) {
                int c = h * 32 + lk * 8 + j;
                float v = -2048.0f * xb[c * HW];
                zsq = fmaf(v, v, zsq);
                _Float16 hi = (_Float16)v;
                _Float16 lo = (_Float16)(v - (float)hi);
                ah[m][h][j] = hi; al[m][h][j] = lo;
            }
        }
        zsq *= (1.0f / 4096.0f);                 // v^2/4096 = 1024*x^2
        zsq += __shfl_xor(zsq, 16, 64);
        zsq += __shfl_xor(zsq, 32, 64);
        znorm[m] = zsq;                           // every lane: full norm of its (m,lrow) point
    }
    // zseed per C-slot: slot (m,r) on this lane is point m*16 + lk*4 + r
    f32x4 zs[4];
    #pragma unroll
    for (int m = 0; m < 4; ++m)
        #pragma unroll
        for (int r = 0; r < 4; ++r)
            zs[m][r] = __shfl(znorm[m], lk * 4 + r, 64) + 512.0f;   // +0.5 d-units bias

    unsigned best[4][4], sec[4][4];
    #pragma unroll
    for (int m = 0; m < 4; ++m)
        #pragma unroll
        for (int r = 0; r < 4; ++r) { best[m][r] = 0xFFFFFFFFu; sec[m][r] = 0xFFFFFFFFu; }

    f16x8 b0A, b1A, b2A, b3A, b0B, b1B, b2B, b3B;
    float n0A, n1A, n0B, n1B;

    auto LOADP = [&](int p, f16x8& v0, f16x8& v1, f16x8& v2, f16x8& v3, float& m0, float& m1) {
        const char* g0 = bp + (2 * p) * GSTRIDE;
        const char* g1 = g0 + GSTRIDE;
        v0 = *(const f16x8*)(g0 + lane * 16);
        v1 = *(const f16x8*)(g0 + 1024 + lane * 16);
        v2 = *(const f16x8*)(g1 + lane * 16);
        v3 = *(const f16x8*)(g1 + 1024 + lane * 16);
        m0 = *(const float*)(g0 + 2048 + lane * 4);
        m1 = *(const float*)(g1 + 2048 + lane * 4);
    };
    auto COMP = [&](int p, const f16x8& v0, const f16x8& v1, const f16x8& v2, const f16x8& v3,
                    float m0, float m1) {
        f32x4 a0[4], a1[4];
        #pragma unroll
        for (int m = 0; m < 4; ++m) a0[m] = __builtin_amdgcn_mfma_f32_16x16x32_f16(ah[m][0], v0, zs[m], 0, 0, 0);
        #pragma unroll
        for (int m = 0; m < 4; ++m) a0[m] = __builtin_amdgcn_mfma_f32_16x16x32_f16(ah[m][1], v1, a0[m], 0, 0, 0);
        #pragma unroll
        for (int m = 0; m < 4; ++m) a0[m] = __builtin_amdgcn_mfma_f32_16x16x32_f16(al[m][0], v0, a0[m], 0, 0, 0);
        #pragma unroll
        for (int m = 0; m < 4; ++m) a0[m] = __builtin_amdgcn_mfma_f32_16x16x32_f16(al[m][1], v1, a0[m], 0, 0, 0);
        #pragma unroll
        for (int m = 0; m < 4; ++m) a1[m] = __builtin_amdgcn_mfma_f32_16x16x32_f16(ah[m][0], v2, zs[m], 0, 0, 0);
        #pragma unroll
        for (int m = 0; m < 4; ++m) a1[m] = __builtin_amdgcn_mfma_f32_16x16x32_f16(ah[m][1], v3, a1[m], 0, 0, 0);
        #pragma unroll
        for (int m = 0; m < 4; ++m) a1[m] = __builtin_amdgcn_mfma_f32_16x16x32_f16(al[m][0], v2, a1[m], 0, 0, 0);
        #pragma unroll
        for (int m = 0; m < 4; ++m) a1[m] = __builtin_amdgcn_mfma_f32_16x16x32_f16(al[m][1], v3, a1[m], 0, 0, 0);

        unsigned code0 = (unsigned)(2 * p * 16) | (unsigned)lrow;
        unsigned code1 = code0 + 16u;
        #pragma unroll
        for (int m = 0; m < 4; ++m) {
            #pragma unroll
            for (int r = 0; r < 4; ++r) {
                float d0 = a0[m][r] + m0;
                float d1 = a1[m][r] + m1;
                unsigned u0 = ((unsigned)d0 << 10) | code0;   // cvt trunc is monotone; code in low bits
                unsigned u1 = ((unsigned)d1 << 10) | code1;
                unsigned md = umed3(best[m][r], u0, u1);      // second-smallest of {best,u0,u1}
                best[m][r] = umin3(best[m][r], u0, u1);
                sec[m][r]  = min(sec[m][r], md);
            }
        }
    };

    LOADP(0, b0A, b1A, b2A, b3A, n0A, n1A);
    for (int it = 0; it < 16; ++it) {
        LOADP(2 * it + 1, b0B, b1B, b2B, b3B, n0B, n1B);      // prefetch
        COMP(2 * it, b0A, b1A, b2A, b3A, n0A, n1A);
        LOADP((2 * it + 2) & 31, b0A, b1A, b2A, b3A, n0A, n1A); // last iter: harmless reload of 0
        COMP(2 * it + 1, b0B, b1B, b2B, b3B, n0B, n1B);
    }

    // ---- reduce over the 16 col-lanes; packed key => ties pick smaller code ----
    #pragma unroll
    for (int m = 0; m < 4; ++m) {
        #pragma unroll
        for (int r = 0; r < 4; ++r) {
            unsigned b_ = best[m][r], s_ = sec[m][r];
            #pragma unroll
            for (int msk = 1; msk < 16; msk <<= 1) {
                unsigned ob = (unsigned)__shfl_xor((int)b_, msk, 64);
                unsigned os = (unsigned)__shfl_xor((int)s_, msk, 64);
                s_ = min(min(s_, os), max(b_, ob));
                b_ = min(b_, ob);
            }
            if (lrow == 0) {
                int pl = m * 16 + lk * 4 + r;
                s_idx[widx][pl] = (int)(b_ & 1023u);
                s_gap[widx][pl] = s_ - b_;
            }
        }
    }
    __syncthreads();

    // ---- epilogue: 1 lane = 1 point ----
    const int p = wb + lane;
    const int myidx = s_idx[widx][lane];
    if (s_gap[widx][lane] < THR_KEY) {
        int slot = atomicAdd(wl_cnt, 1);
        if (slot < WLCAP) wl[slot] = p;
    }
    out[1 + NELEM + p] = (float)myidx;

    const int b = p >> 12, sp = p & (HW - 1);
    const float*  xr   = x + b * CHW + sp;
    float*        orow = out + 1 + b * CHW + sp;
    const float4* er   = (const float4*)(emb + myidx * CDIM);
    float lsum = 0.f;
    #pragma unroll
    for (int c4 = 0; c4 < CDIM / 4; ++c4) {
        float4 q = er[c4];
        float qq[4] = {q.x, q.y, q.z, q.w};
        #pragma unroll
        for (int t = 0; t < 4; ++t) {
            int c = c4 * 4 + t;
            float xv = xr[c * HW];
            float d = qq[t] - xv;
            lsum += d * d;
            orow[c * HW] = qq[t];
        }
    }
    #pragma unroll
    for (int off = 32; off > 0; off >>= 1)
        lsum += __shfl_down(lsum, off, 64);
    if (lane == 0) atomicAdd(ws, lsum);
}

// Exact f64 rescan for flagged points — restructured for coalesced codebook
// access: 4 codes per iteration, 16 lanes per code (one contiguous 1KB
// wave-load per iter, vs 64-way scattered lines in the old layout).
__global__ __launch_bounds__(256) void vq_fallback(
    const float* __restrict__ x, const float* __restrict__ emb,
    float* __restrict__ ws, float* __restrict__ out)
{
    const int* wl_cnt = (const int*)(ws + WS_WL);
    const int* wl = wl_cnt + 16;
    const int lane = threadIdx.x & 63;
    const int widx = threadIdx.x >> 6;
    const int wslot = blockIdx.x * 4 + widx;          // 0..2047
    int cnt = *wl_cnt;
    if (cnt > WLCAP) cnt = WLCAP;

    __shared__ float zsh[4][64];

    const int sub  = lane >> 4;      // which of the 4 codes this lane helps
    const int quad = lane & 15;      // dim-quartet index within the code row

    for (int i = wslot; i < cnt; i += 4 * NFB_BLOCKS) {
        const int p = wl[i];
        const int b = p >> 12, sp = p & (HW - 1);
        const float* xr = x + b * CHW + sp;

        // stage z through LDS: ONE column-gather instruction, then per-lane quartet
        zsh[widx][lane] = xr[lane * HW];
        float4 zq = *(const float4*)&zsh[widx][quad * 4];   // same-wave dep; compiler waits
        double z0 = zq.x, z1 = zq.y, z2 = zq.z, z3 = zq.w;

        double best = 1e300;
        int    bi   = 0;
        for (int base = 0; base < KCODES; base += 4) {
            // contiguous 1KB per wave: rows base..base+3, 16 lanes x float4 each
            const float4 e = *(const float4*)(emb + (base + sub) * CDIM + quad * 4);
            double t0 = z0 - (double)e.x;
            double t1 = z1 - (double)e.y;
            double t2 = z2 - (double)e.z;
            double t3 = z3 - (double)e.w;
            double s = t0 * t0 + t1 * t1 + t2 * t2 + t3 * t3;
            s += __shfl_xor(s, 1, 64);
            s += __shfl_xor(s, 2, 64);
            s += __shfl_xor(s, 4, 64);
            s += __shfl_xor(s, 8, 64);                       // 16-lane group sum
            if (s < best) { best = s; bi = base + sub; }     // ascending base -> first idx per sub
        }
        // merge the 4 sub-groups; ties -> smaller code index
        #pragma unroll
        for (int msk = 16; msk < 64; msk <<= 1) {
            double od = __shfl_xor(best, msk, 64);
            int    oi = __shfl_xor(bi,   msk, 64);
            bool take = (od < best) || (od == best && oi < bi);
            best = take ? od : best;
            bi   = take ? oi : bi;
        }

        const int oldidx = (int)out[1 + NELEM + p];
        if (bi != oldidx) {
            if (lane == 0) out[1 + NELEM + p] = (float)bi;
            float xv = zsh[widx][lane];
            float qn = emb[bi * CDIM + lane];
            float qo = emb[oldidx * CDIM + lane];
            out[1 + b * CHW + lane * HW + sp] = qn;
            float dl = (qn - xv) * (qn - xv) - (qo - xv) * (qo - xv);
            #pragma unroll
            for (int off = 32; off > 0; off >>= 1)
                dl += __shfl_down(dl, off, 64);
            if (lane == 0) atomicAdd(ws, dl);
        }
    }
}

__global__ void vq_final(const float* __restrict__ ws, float* __restrict__ out) {
    if (threadIdx.x == 0 && blockIdx.x == 0)
        out[0] = 0.25f * ws[0] / (float)NELEM;
}

extern "C" void kernel_launch(void* const* d_in, const int* in_sizes, int n_in,
                              void* d_out, int out_size, void* d_ws, size_t ws_size,
                              hipStream_t stream) {
    const float* x   = (const float*)d_in[0];
    const float* emb = (const float*)d_in[1];
    float* out = (float*)d_out;
    float* ws  = (float*)d_ws;

    vq_prep<<<16, 256, 0, stream>>>(emb, ws);
    vq_main<<<NPTS / 256, 256, 0, stream>>>(x, emb, ws, out);
    vq_fallback<<<NFB_BLOCKS, 256, 0, stream>>>(x, emb, ws, out);
    vq_final<<<1, 64, 0, stream>>>(ws, out);
}

// Round 6
// 349.967 us; speedup vs baseline: 1.0959x; 1.0959x over previous
//
#include <hip/hip_runtime.h>

// Problem constants (B,C,H,W = 32,64,64,64; K=1024)
#define NPTS   131072
#define CDIM   64
#define KCODES 1024
#define HW     4096
#define CHW    (CDIM*HW)
#define NELEM  8388608

#define NGROUP  64              // 1024 codes / 16 per MFMA col-tile
#define GSTRIDE 2304            // bytes/group: 1024 (hi half0) + 1024 (hi half1) + 256 (norms*1024)
#define WS_BP   8               // float offset of Bpack in ws
#define WS_WL   (WS_BP + (NGROUP*GSTRIDE)/4)   // = 36872 (floats); wl_cnt, wl after +16
#define WLCAP   16384
#define WS_ET   (WS_WL + 16 + WLCAP)           // = 53272 (floats); embT[64][1024]
#define WS_END  (WS_ET + CDIM*KCODES)          // = 118808 floats = 475232 B
#define NFB_BLOCKS 512          // 2048 fallback waves
#define THR_KEY (256u << 10)    // 256 granules = 0.25 in true-distance units

typedef __attribute__((ext_vector_type(8))) _Float16 f16x8;
typedef __attribute__((ext_vector_type(4))) float    f32x4;

__device__ inline unsigned umin3(unsigned a, unsigned b, unsigned c) {
    unsigned d; asm("v_min3_u32 %0, %1, %2, %3" : "=v"(d) : "v"(a), "v"(b), "v"(c)); return d;
}
__device__ inline unsigned umed3(unsigned a, unsigned b, unsigned c) {
    unsigned d; asm("v_med3_u32 %0, %1, %2, %3" : "=v"(d) : "v"(a), "v"(b), "v"(c)); return d;
}

// Build the lane-order packed codebook (for vq_main) and, if do_et, the
// column-major copy embT[dim][code] (for the fast fallback).
__global__ void vq_prep(const float* __restrict__ emb, float* __restrict__ ws, int do_et) {
    int t = blockIdx.x * 256 + threadIdx.x;          // grid 16*256 = 4096
    if (t == 0) { ws[0] = 0.0f; ((int*)(ws + WS_WL))[0] = 0; }
    int g = t >> 6, l = t & 63;
    int code = g * 16 + (l & 15);
    int ch0  = (l >> 4) * 8;
    char* bp = (char*)(ws + WS_BP) + g * GSTRIDE;
    const float* row = emb + code * CDIM;
    double s = 0.0;
    for (int c = 0; c < CDIM; ++c) { double v = row[c]; s += v * v; }
    *(float*)(bp + 2048 + l * 4) = (float)(s * 1024.0);   // ||e||^2 * 1024
    f16x8 h0, h1;
    #pragma unroll
    for (int j = 0; j < 8; ++j) {
        h0[j] = (_Float16)row[ch0 + j];
        h1[j] = (_Float16)row[32 + ch0 + j];
    }
    *(f16x8*)(bp + l * 16)        = h0;
    *(f16x8*)(bp + 1024 + l * 16) = h1;

    if (do_et) {
        // thread t -> dim c = t&63, code block kb = (t>>6)*16.
        // Reads coalesced across lanes (one emb row = 256B); each lane writes
        // its own contiguous 64B embT segment as 4x float4.
        int c  = t & 63;
        int kb = (t >> 6) * 16;
        #pragma unroll
        for (int jj = 0; jj < 4; ++jj) {
            float4 v;
            v.x = emb[(kb + jj * 4 + 0) * CDIM + c];
            v.y = emb[(kb + jj * 4 + 1) * CDIM + c];
            v.z = emb[(kb + jj * 4 + 2) * CDIM + c];
            v.w = emb[(kb + jj * 4 + 3) * CDIM + c];
            *(float4*)&ws[WS_ET + c * KCODES + kb + jj * 4] = v;
        }
    }
}

// 256 threads = 4 waves; each wave owns 64 consecutive points.  (unchanged)
__global__ __launch_bounds__(256, 2) void vq_main(
    const float* __restrict__ x, const float* __restrict__ emb,
    float* __restrict__ ws, float* __restrict__ out)
{
    const char* bp = (const char*)(ws + WS_BP);
    int* wl_cnt = (int*)(ws + WS_WL);
    int* wl = wl_cnt + 16;

    const int lane = threadIdx.x & 63;
    const int widx = threadIdx.x >> 6;
    const int wb   = (blockIdx.x * 4 + widx) * 64;
    const int lrow = lane & 15;
    const int lk   = lane >> 4;

    __shared__ int      s_idx[4][64];
    __shared__ unsigned s_gap[4][64];

    f16x8 ah[4][2], al[4][2];
    float znorm[4];
    #pragma unroll
    for (int m = 0; m < 4; ++m) {
        int p = wb + m * 16 + lrow;
        const float* xb = x + (p >> 12) * CHW + (p & (HW - 1));
        float zsq = 0.f;
        #pragma unroll
        for (int h = 0; h < 2; ++h) {
            #pragma unroll
            for (int j = 0; j < 8; ++j) {
                int c = h * 32 + lk * 8 + j;
                float v = -2048.0f * xb[c * HW];
                zsq = fmaf(v, v, zsq);
                _Float16 hi = (_Float16)v;
                _Float16 lo = (_Float16)(v - (float)hi);
                ah[m][h][j] = hi; al[m][h][j] = lo;
            }
        }
        zsq *= (1.0f / 4096.0f);
        zsq += __shfl_xor(zsq, 16, 64);
        zsq += __shfl_xor(zsq, 32, 64);
        znorm[m] = zsq;
    }
    f32x4 zs[4];
    #pragma unroll
    for (int m = 0; m < 4; ++m)
        #pragma unroll
        for (int r = 0; r < 4; ++r)
            zs[m][r] = __shfl(znorm[m], lk * 4 + r, 64) + 512.0f;

    unsigned best[4][4], sec[4][4];
    #pragma unroll
    for (int m = 0; m < 4; ++m)
        #pragma unroll
        for (int r = 0; r < 4; ++r) { best[m][r] = 0xFFFFFFFFu; sec[m][r] = 0xFFFFFFFFu; }

    f16x8 b0A, b1A, b2A, b3A, b0B, b1B, b2B, b3B;
    float n0A, n1A, n0B, n1B;

    auto LOADP = [&](int p, f16x8& v0, f16x8& v1, f16x8& v2, f16x8& v3, float& m0, float& m1) {
        const char* g0 = bp + (2 * p) * GSTRIDE;
        const char* g1 = g0 + GSTRIDE;
        v0 = *(const f16x8*)(g0 + lane * 16);
        v1 = *(const f16x8*)(g0 + 1024 + lane * 16);
        v2 = *(const f16x8*)(g1 + lane * 16);
        v3 = *(const f16x8*)(g1 + 1024 + lane * 16);
        m0 = *(const float*)(g0 + 2048 + lane * 4);
        m1 = *(const float*)(g1 + 2048 + lane * 4);
    };
    auto COMP = [&](int p, const f16x8& v0, const f16x8& v1, const f16x8& v2, const f16x8& v3,
                    float m0, float m1) {
        f32x4 a0[4], a1[4];
        #pragma unroll
        for (int m = 0; m < 4; ++m) a0[m] = __builtin_amdgcn_mfma_f32_16x16x32_f16(ah[m][0], v0, zs[m], 0, 0, 0);
        #pragma unroll
        for (int m = 0; m < 4; ++m) a0[m] = __builtin_amdgcn_mfma_f32_16x16x32_f16(ah[m][1], v1, a0[m], 0, 0, 0);
        #pragma unroll
        for (int m = 0; m < 4; ++m) a0[m] = __builtin_amdgcn_mfma_f32_16x16x32_f16(al[m][0], v0, a0[m], 0, 0, 0);
        #pragma unroll
        for (int m = 0; m < 4; ++m) a0[m] = __builtin_amdgcn_mfma_f32_16x16x32_f16(al[m][1], v1, a0[m], 0, 0, 0);
        #pragma unroll
        for (int m = 0; m < 4; ++m) a1[m] = __builtin_amdgcn_mfma_f32_16x16x32_f16(ah[m][0], v2, zs[m], 0, 0, 0);
        #pragma unroll
        for (int m = 0; m < 4; ++m) a1[m] = __builtin_amdgcn_mfma_f32_16x16x32_f16(ah[m][1], v3, a1[m], 0, 0, 0);
        #pragma unroll
        for (int m = 0; m < 4; ++m) a1[m] = __builtin_amdgcn_mfma_f32_16x16x32_f16(al[m][0], v2, a1[m], 0, 0, 0);
        #pragma unroll
        for (int m = 0; m < 4; ++m) a1[m] = __builtin_amdgcn_mfma_f32_16x16x32_f16(al[m][1], v3, a1[m], 0, 0, 0);

        unsigned code0 = (unsigned)(2 * p * 16) | (unsigned)lrow;
        unsigned code1 = code0 + 16u;
        #pragma unroll
        for (int m = 0; m < 4; ++m) {
            #pragma unroll
            for (int r = 0; r < 4; ++r) {
                float d0 = a0[m][r] + m0;
                float d1 = a1[m][r] + m1;
                unsigned u0 = ((unsigned)d0 << 10) | code0;
                unsigned u1 = ((unsigned)d1 << 10) | code1;
                unsigned md = umed3(best[m][r], u0, u1);
                best[m][r] = umin3(best[m][r], u0, u1);
                sec[m][r]  = min(sec[m][r], md);
            }
        }
    };

    LOADP(0, b0A, b1A, b2A, b3A, n0A, n1A);
    for (int it = 0; it < 16; ++it) {
        LOADP(2 * it + 1, b0B, b1B, b2B, b3B, n0B, n1B);
        COMP(2 * it, b0A, b1A, b2A, b3A, n0A, n1A);
        LOADP((2 * it + 2) & 31, b0A, b1A, b2A, b3A, n0A, n1A);
        COMP(2 * it + 1, b0B, b1B, b2B, b3B, n0B, n1B);
    }

    #pragma unroll
    for (int m = 0; m < 4; ++m) {
        #pragma unroll
        for (int r = 0; r < 4; ++r) {
            unsigned b_ = best[m][r], s_ = sec[m][r];
            #pragma unroll
            for (int msk = 1; msk < 16; msk <<= 1) {
                unsigned ob = (unsigned)__shfl_xor((int)b_, msk, 64);
                unsigned os = (unsigned)__shfl_xor((int)s_, msk, 64);
                s_ = min(min(s_, os), max(b_, ob));
                b_ = min(b_, ob);
            }
            if (lrow == 0) {
                int pl = m * 16 + lk * 4 + r;
                s_idx[widx][pl] = (int)(b_ & 1023u);
                s_gap[widx][pl] = s_ - b_;
            }
        }
    }
    __syncthreads();

    const int p = wb + lane;
    const int myidx = s_idx[widx][lane];
    if (s_gap[widx][lane] < THR_KEY) {
        int slot = atomicAdd(wl_cnt, 1);
        if (slot < WLCAP) wl[slot] = p;
    }
    out[1 + NELEM + p] = (float)myidx;

    const int b = p >> 12, sp = p & (HW - 1);
    const float*  xr   = x + b * CHW + sp;
    float*        orow = out + 1 + b * CHW + sp;
    const float4* er   = (const float4*)(emb + myidx * CDIM);
    float lsum = 0.f;
    #pragma unroll
    for (int c4 = 0; c4 < CDIM / 4; ++c4) {
        float4 q = er[c4];
        float qq[4] = {q.x, q.y, q.z, q.w};
        #pragma unroll
        for (int t = 0; t < 4; ++t) {
            int c = c4 * 4 + t;
            float xv = xr[c * HW];
            float d = qq[t] - xv;
            lsum += d * d;
            orow[c * HW] = qq[t];
        }
    }
    #pragma unroll
    for (int off = 32; off > 0; off >>= 1)
        lsum += __shfl_down(lsum, off, 64);
    if (lane == 0) atomicAdd(ws, lsum);
}

// FAST exact f64 rescan: lane-owns-code over column-major embT.
// No cross-lane ops in the inner loop; 1KB contiguous wave-load per dim.
__global__ __launch_bounds__(256) void vq_fallback_fast(
    const float* __restrict__ x, const float* __restrict__ emb,
    float* __restrict__ ws, float* __restrict__ out)
{
    const int* wl_cnt = (const int*)(ws + WS_WL);
    const int* wl = wl_cnt + 16;
    const float* embT = ws + WS_ET;
    const int lane = threadIdx.x & 63;
    const int widx = threadIdx.x >> 6;
    const int wslot = blockIdx.x * 4 + widx;
    int cnt = *wl_cnt;
    if (cnt > WLCAP) cnt = WLCAP;

    __shared__ float zsh[4][64];

    for (int i = wslot; i < cnt; i += 4 * NFB_BLOCKS) {
        const int p = wl[i];
        const int b = p >> 12, sp = p & (HW - 1);
        const float* xr = x + b * CHW + sp;
        zsh[widx][lane] = xr[lane * HW];     // one column-gather; same-wave LDS dep

        double bd = 1e300; int bi = 0;
        for (int pass = 0; pass < 4; ++pass) {
            const int code0 = pass * 256 + lane * 4;
            const float* ecol = embT + code0;
            double s0 = 0.0, s1 = 0.0, s2 = 0.0, s3 = 0.0;
            #pragma unroll 16
            for (int c = 0; c < CDIM; ++c) {
                float4 e = *(const float4*)(ecol + c * KCODES);  // wave: 1KB contiguous
                double zc = (double)zsh[widx][c];                // LDS broadcast
                double t0 = zc - (double)e.x;
                double t1 = zc - (double)e.y;
                double t2 = zc - (double)e.z;
                double t3 = zc - (double)e.w;
                s0 = fma(t0, t0, s0);
                s1 = fma(t1, t1, s1);
                s2 = fma(t2, t2, s2);
                s3 = fma(t3, t3, s3);
            }
            if (s0 < bd) { bd = s0; bi = code0 + 0; }   // ascending code: first on ties
            if (s1 < bd) { bd = s1; bi = code0 + 1; }
            if (s2 < bd) { bd = s2; bi = code0 + 2; }
            if (s3 < bd) { bd = s3; bi = code0 + 3; }
        }
        #pragma unroll
        for (int msk = 1; msk < 64; msk <<= 1) {
            double od = __shfl_xor(bd, msk, 64);
            int    oi = __shfl_xor(bi, msk, 64);
            bool take = (od < bd) || (od == bd && oi < bi);
            bd = take ? od : bd;
            bi = take ? oi : bi;
        }
        const int oldidx = (int)out[1 + NELEM + p];
        if (bi != oldidx) {
            if (lane == 0) out[1 + NELEM + p] = (float)bi;
            float xv = zsh[widx][lane];
            float qn = emb[bi * CDIM + lane];
            float qo = emb[oldidx * CDIM + lane];
            out[1 + b * CHW + lane * HW + sp] = qn;
            float dl = (qn - xv) * (qn - xv) - (qo - xv) * (qo - xv);
            #pragma unroll
            for (int off = 32; off > 0; off >>= 1)
                dl += __shfl_down(dl, off, 64);
            if (lane == 0) atomicAdd(ws, dl);
        }
    }
}

// Backup (round-5 validated) fallback for the case ws is too small for embT.
__global__ __launch_bounds__(256) void vq_fallback(
    const float* __restrict__ x, const float* __restrict__ emb,
    float* __restrict__ ws, float* __restrict__ out)
{
    const int* wl_cnt = (const int*)(ws + WS_WL);
    const int* wl = wl_cnt + 16;
    const int lane = threadIdx.x & 63;
    const int widx = threadIdx.x >> 6;
    const int wslot = blockIdx.x * 4 + widx;
    int cnt = *wl_cnt;
    if (cnt > WLCAP) cnt = WLCAP;

    __shared__ float zsh[4][64];
    const int sub  = lane >> 4;
    const int quad = lane & 15;

    for (int i = wslot; i < cnt; i += 4 * NFB_BLOCKS) {
        const int p = wl[i];
        const int b = p >> 12, sp = p & (HW - 1);
        const float* xr = x + b * CHW + sp;
        zsh[widx][lane] = xr[lane * HW];
        float4 zq = *(const float4*)&zsh[widx][quad * 4];
        double z0 = zq.x, z1 = zq.y, z2 = zq.z, z3 = zq.w;

        double best = 1e300;
        int    bi   = 0;
        for (int base = 0; base < KCODES; base += 4) {
            const float4 e = *(const float4*)(emb + (base + sub) * CDIM + quad * 4);
            double t0 = z0 - (double)e.x;
            double t1 = z1 - (double)e.y;
            double t2 = z2 - (double)e.z;
            double t3 = z3 - (double)e.w;
            double s = t0 * t0 + t1 * t1 + t2 * t2 + t3 * t3;
            s += __shfl_xor(s, 1, 64);
            s += __shfl_xor(s, 2, 64);
            s += __shfl_xor(s, 4, 64);
            s += __shfl_xor(s, 8, 64);
            if (s < best) { best = s; bi = base + sub; }
        }
        #pragma unroll
        for (int msk = 16; msk < 64; msk <<= 1) {
            double od = __shfl_xor(best, msk, 64);
            int    oi = __shfl_xor(bi,   msk, 64);
            bool take = (od < best) || (od == best && oi < bi);
            best = take ? od : best;
            bi   = take ? oi : bi;
        }
        const int oldidx = (int)out[1 + NELEM + p];
        if (bi != oldidx) {
            if (lane == 0) out[1 + NELEM + p] = (float)bi;
            float xv = zsh[widx][lane];
            float qn = emb[bi * CDIM + lane];
            float qo = emb[oldidx * CDIM + lane];
            out[1 + b * CHW + lane * HW + sp] = qn;
            float dl = (qn - xv) * (qn - xv) - (qo - xv) * (qo - xv);
            #pragma unroll
            for (int off = 32; off > 0; off >>= 1)
                dl += __shfl_down(dl, off, 64);
            if (lane == 0) atomicAdd(ws, dl);
        }
    }
}

__global__ void vq_final(const float* __restrict__ ws, float* __restrict__ out) {
    if (threadIdx.x == 0 && blockIdx.x == 0)
        out[0] = 0.25f * ws[0] / (float)NELEM;
}

extern "C" void kernel_launch(void* const* d_in, const int* in_sizes, int n_in,
                              void* d_out, int out_size, void* d_ws, size_t ws_size,
                              hipStream_t stream) {
    const float* x   = (const float*)d_in[0];
    const float* emb = (const float*)d_in[1];
    float* out = (float*)d_out;
    float* ws  = (float*)d_ws;

    const int fast = (ws_size >= (size_t)WS_END * 4) ? 1 : 0;  // deterministic per process

    vq_prep<<<16, 256, 0, stream>>>(emb, ws, fast);
    vq_main<<<NPTS / 256, 256, 0, stream>>>(x, emb, ws, out);
    if (fast)
        vq_fallback_fast<<<NFB_BLOCKS, 256, 0, stream>>>(x, emb, ws, out);
    else
        vq_fallback<<<NFB_BLOCKS, 256, 0, stream>>>(x, emb, ws, out);
    vq_final<<<1, 64, 0, stream>>>(ws, out);
}